// Round 1
// baseline (118.362 us; speedup 1.0000x reference)
//
#include <hip/hip_runtime.h>

// Real solid spherical harmonics up to l=6 (49 outputs) for N points.
// Structure (dst, px, py, pz, clm) is a deterministic function of max_l=6 and is
// replicated here at compile time (clm = +-0.25^t * product of binomials -> exactly
// representable in fp32). ns_lms (contains sqrt of factorials) is read from d_in[2].

namespace {

constexpr int MAXL   = 6;
constexpr int NOUT   = (MAXL + 1) * (MAXL + 1);  // 49
constexpr int NT_MAX = 256;

struct Tab {
    int   dst[NT_MAX];
    int   px[NT_MAX];
    int   py[NT_MAX];
    int   pz[NT_MAX];
    float clm[NT_MAX];
    int   cnt;
};

constexpr long long comb(int n, int k) {
    if (k < 0 || k > n) return 0;
    long long r = 1;
    for (int i = 0; i < k; ++i) r = r * (n - i) / (i + 1);  // exact at each step
    return r;
}

constexpr Tab build_tab() {
    Tab tb{};
    int k = 0;
    for (int l = 0; l <= MAXL; ++l) {
        for (int m = -l; m <= l; ++m) {
            const int am  = (m < 0) ? -m : m;
            const int v2s = (m < 0) ? 1 : 0;
            const int v2e = 2 * ((m < 0) ? (am - 1) / 2 : am / 2) + v2s;
            for (int t = 0; t <= (l - am) / 2; ++t) {
                for (int u = 0; u <= t; ++u) {
                    for (int v2 = v2s; v2 <= v2e; v2 += 2) {
                        const int parity = (t + (v2 - v2s) / 2) % 2;
                        double c = parity ? -1.0 : 1.0;
                        for (int i = 0; i < t; ++i) c *= 0.25;
                        c *= (double)comb(l, t);
                        c *= (double)((am + t <= l - t) ? comb(l - t, am + t) : 0);
                        c *= (double)comb(t, u);
                        c *= (double)((v2 <= am) ? comb(am, v2) : 0);
                        tb.dst[k] = l * (l + 1) + m;
                        tb.px[k]  = 2 * t + am - 2 * u - v2;
                        tb.py[k]  = 2 * u + v2;
                        tb.pz[k]  = l - 2 * t - am;
                        tb.clm[k] = (float)c;
                        ++k;
                    }
                }
            }
        }
    }
    tb.cnt = k;
    return tb;
}

constexpr Tab TB = build_tab();
static_assert(TB.cnt == 188, "expected 188 terms for max_l=6");

constexpr int BLOCK = 256;

}  // namespace

__global__ __launch_bounds__(BLOCK) void rsh_kernel(const float* __restrict__ xyz,
                                                    const float* __restrict__ ns,
                                                    float* __restrict__ out,
                                                    int N) {
    __shared__ float sm[BLOCK * NOUT];  // 49 KiB: per-thread outputs, transposed store

    const int tid = threadIdx.x;
    const long long i = (long long)blockIdx.x * BLOCK + tid;

    float x = 0.f, y = 0.f, z = 0.f;
    if (i < N) {
        const float* p = xyz + i * 3;
        x = p[0]; y = p[1]; z = p[2];
    }

    // power tables in registers (static indexing only)
    float xp[MAXL + 1], yp[MAXL + 1], zp[MAXL + 1];
    xp[0] = yp[0] = zp[0] = 1.f;
#pragma unroll
    for (int p = 1; p <= MAXL; ++p) {
        xp[p] = xp[p - 1] * x;
        yp[p] = yp[p - 1] * y;
        zp[p] = zp[p - 1] * z;
    }

    float acc[NOUT];
#pragma unroll
    for (int o = 0; o < NOUT; ++o) acc[o] = 0.f;

    // fully unrolled: all indices fold to compile-time constants
#pragma unroll
    for (int k = 0; k < TB.cnt; ++k) {
        const float mono = xp[TB.px[k]] * yp[TB.py[k]] * zp[TB.pz[k]];
        acc[TB.dst[k]] = fmaf(TB.clm[k], mono, acc[TB.dst[k]]);
    }

    // scale by ns (uniform scalar loads) and stage to LDS.
    // stride 49 (odd) -> 64 lanes spread over all 32 banks, 2/bank = free.
#pragma unroll
    for (int o = 0; o < NOUT; ++o) sm[tid * NOUT + o] = acc[o] * ns[o];

    __syncthreads();

    // cooperative, coalesced float4 store of the block's contiguous output slab
    const float4* sm4 = (const float4*)sm;
    float4* out4 = (float4*)out;
    const long long base4 = (long long)blockIdx.x * (BLOCK * NOUT / 4);
    const long long lim4 = (long long)N * NOUT / 4;  // N*49 divisible by 4 here
#pragma unroll 1
    for (int idx = tid; idx < BLOCK * NOUT / 4; idx += BLOCK) {
        const long long g = base4 + idx;
        if (g < lim4) out4[g] = sm4[idx];
    }
}

extern "C" void kernel_launch(void* const* d_in, const int* in_sizes, int n_in,
                              void* d_out, int out_size, void* d_ws, size_t ws_size,
                              hipStream_t stream) {
    const float* xyz = (const float*)d_in[0];
    const float* ns  = (const float*)d_in[2];  // ns_lms [49]
    float* out = (float*)d_out;

    const int N = in_sizes[0] / 3;
    const int grid = (N + BLOCK - 1) / BLOCK;
    rsh_kernel<<<grid, BLOCK, 0, stream>>>(xyz, ns, out, N);
}